// Round 9
// baseline (1805.210 us; speedup 1.0000x reference)
//
#include <hip/hip_runtime.h>

#define B_   128
#define S_   256
#define D_   512
#define L_   4
#define H_   8
#define DH_  64
#define FF_  512
#define M_   32768   // B_*S_
#define EPS_ 1e-3f

typedef unsigned short u16;
typedef unsigned int   u32;
typedef __bf16 bf16_8 __attribute__((ext_vector_type(8)));
typedef float  f32_4  __attribute__((ext_vector_type(4)));

__device__ __forceinline__ float bf2f(u16 u) {
  union { u32 i; float f; } x; x.i = ((u32)u) << 16; return x.f;
}
__device__ __forceinline__ u16 f2bf(float f) {
  union { float f; u32 i; } x; x.f = f;
  u32 r = x.i + 0x7fffu + ((x.i >> 16) & 1u);
  return (u16)(r >> 16);
}
// async 16B global->LDS; lane i of the wave lands at l + i*16 bytes
__device__ __forceinline__ void async_cp16(const void* g, void* l) {
  __builtin_amdgcn_global_load_lds(
      (const __attribute__((address_space(1))) void*)g,
      (__attribute__((address_space(3))) void*)l, 16, 0, 0);
}

// ---------------- embedding: h_bf16 = bf16(embed[seq] + pos), f32 inputs ----------------
__global__ __launch_bounds__(256) void k_embed(const int* __restrict__ seq,
    const float* __restrict__ pos, const float* __restrict__ emb,
    u16* __restrict__ h)
{
  int t = blockIdx.x * 256 + threadIdx.x;   // M_*64 threads, 8 elems each
  int row = t >> 6;
  int c = (t & 63) * 8;
  int s = row & (S_ - 1);
  int tok = seq[row];
  const float* ep = emb + (size_t)tok * D_ + c;
  const float* pp = pos + (size_t)s * D_ + c;
  float4 e0 = *(const float4*)ep;
  float4 e1 = *(const float4*)(ep + 4);
  float4 p0 = *(const float4*)pp;
  float4 p1 = *(const float4*)(pp + 4);
  u32 o[4];
  o[0] = (u32)f2bf(e0.x + p0.x) | ((u32)f2bf(e0.y + p0.y) << 16);
  o[1] = (u32)f2bf(e0.z + p0.z) | ((u32)f2bf(e0.w + p0.w) << 16);
  o[2] = (u32)f2bf(e1.x + p1.x) | ((u32)f2bf(e1.y + p1.y) << 16);
  o[3] = (u32)f2bf(e1.z + p1.z) | ((u32)f2bf(e1.w + p1.w) << 16);
  *(uint4*)&h[(size_t)row * D_ + c] = make_uint4(o[0], o[1], o[2], o[3]);
}

// ------- transpose all 24 [512x512] f32 weights -> bf16 Wt[n][k] -------
__global__ __launch_bounds__(256) void k_transpose(
    const float* __restrict__ Wq, const float* __restrict__ Wk, const float* __restrict__ Wv,
    const float* __restrict__ Wo, const float* __restrict__ W1, const float* __restrict__ W2,
    u16* __restrict__ Wt)
{
  __shared__ u16 tile[32][33];
  int mat = blockIdx.z;           // 0..23
  int layer = mat / 6, w = mat % 6;
  const float* src = (w == 0) ? Wq : (w == 1) ? Wk : (w == 2) ? Wv
                   : (w == 3) ? Wo : (w == 4) ? W1 : W2;
  src += (size_t)layer * (D_ * D_);
  u16* dst = Wt + (size_t)mat * (D_ * D_);
  int bx = blockIdx.x * 32;   // n
  int by = blockIdx.y * 32;   // k
  int tx = threadIdx.x & 31, ty = threadIdx.x >> 5;
#pragma unroll
  for (int i = 0; i < 32; i += 8)
    tile[ty + i][tx] = f2bf(src[(size_t)(by + ty + i) * D_ + bx + tx]);
  __syncthreads();
#pragma unroll
  for (int i = 0; i < 32; i += 8)
    dst[(size_t)(bx + ty + i) * D_ + by + tx] = tile[tx][ty + i];
}

// ------- pack per-layer QKV bias into [L][1536] -------
__global__ __launch_bounds__(256) void k_packbias(const float* __restrict__ bq,
    const float* __restrict__ bk, const float* __restrict__ bv, float* __restrict__ dst)
{
  int t = blockIdx.x * 256 + threadIdx.x;   // 4*1536 = 6144
  int l = t / 1536, j = t - l * 1536;
  const float* src = (j < 512) ? bq : (j < 1024) ? bk : bv;
  dst[t] = src[l * 512 + (j & 511)];
}

// ---------------- GEMM: C[M,N] = A[M,512](bf16) x Bt[n][k](bf16) + bias(f32) ----------------
// mode 0: outb bf16 = A*B + bias                      (row-major [M,512])
// mode 1: outb bf16 = relu(A*B + bias)                (row-major [M,512])
// mode 2: outb bf16 = A*B + bias + resid(bf16) (pre-BN value), BN-stat atomics into stats[]
// mode 3: fused QKV (N=1536): outb bf16 head-blocked [b,h,s,dh]; col>>9 selects
//         the q/k/v output buffer (contiguous at stride M_*D_ from outb)
// K-loop: 3-buffer distance-2 prefetch, counted vmcnt (verified round 4).
// Epilogue: acc -> swizzled LDS C-tile -> full-sector uint4 stores (verified round 6).
// Grid is (N-tiles, M-tiles): consecutive blocks share the A m-tile (L2-hot).
__global__ __launch_bounds__(256) void k_gemm(
    const u16* __restrict__ A, const u16* __restrict__ Bt,
    const float* __restrict__ bias, const u16* __restrict__ resid,
    u16* __restrict__ outb, float* __restrict__ stats,
    int mode)
{
  __shared__ __align__(16) u16 smem[24576];   // As(12288) | Bs(12288); epilogue Ct[128][128]
  u16* As = smem;
  u16* Bs = smem + 12288;
  int tid = threadIdx.x;
  int m0 = blockIdx.y * 128;
  int n0 = blockIdx.x * 128;
  int w = tid >> 6, lane = tid & 63;
  int wm = (w >> 1) * 64, wn = (w & 1) * 64;
  int fr = lane & 15, lk = lane >> 4;

  // staging: wave w stages rows [w*32, w*32+32) of A and B tiles via 2 cp16 each.
  int srow = lane >> 2;                          // 0..15 within 16-row window
  int schunk = (lane & 3) ^ ((lane >> 4) & 3);   // swizzled 16B chunk within 64B row
  const u16* Ag0 = A  + (size_t)(m0 + w * 32 + srow) * 512 + schunk * 8;
  const u16* Ag1 = Ag0 + (size_t)16 * 512;
  const u16* Bg0 = Bt + (size_t)(n0 + w * 32 + srow) * 512 + schunk * 8;
  const u16* Bg1 = Bg0 + (size_t)16 * 512;
  int off0 = (w * 32) * 32;
  int off1 = (w * 32 + 16) * 32;

  f32_4 acc[4][4] = {};
  int ach = (lk ^ ((fr >> 2) & 3)) * 8;          // frag chunk (elements) after swizzle

  // prologue: stage k-tiles 0,1 into buffers 0,1 (8 loads in flight/wave)
  async_cp16(Ag0, &As[off0]);
  async_cp16(Ag1, &As[off1]);
  async_cp16(Bg0, &Bs[off0]);
  async_cp16(Bg1, &Bs[off1]);
  async_cp16(Ag0 + 32, &As[4096 + off0]);
  async_cp16(Ag1 + 32, &As[4096 + off1]);
  async_cp16(Bg0 + 32, &Bs[4096 + off0]);
  async_cp16(Bg1 + 32, &Bs[4096 + off1]);

#pragma unroll
  for (int it = 0; it < 16; it++) {
    // wait for the OLDEST tile only: tile it's 4 loads done, tile it+1's may fly
    if (it < 15) asm volatile("s_waitcnt vmcnt(4)" ::: "memory");
    else         asm volatile("s_waitcnt vmcnt(0)" ::: "memory");
    __builtin_amdgcn_s_barrier();
    asm volatile("" ::: "memory");   // fence: no LDS-read hoisting above barrier
    if (it < 14) {                   // stage tile it+2 into buffer (it+2)%3
      int kn = (it + 2) * 32;
      int pn = ((it + 2) % 3) * 4096;
      async_cp16(Ag0 + kn, &As[pn + off0]);
      async_cp16(Ag1 + kn, &As[pn + off1]);
      async_cp16(Bg0 + kn, &Bs[pn + off0]);
      async_cp16(Bg1 + kn, &Bs[pn + off1]);
    }
    const u16* Ab = &As[(it % 3) * 4096];
    const u16* Bb = &Bs[(it % 3) * 4096];
    bf16_8 afr[4], bfr[4];
#pragma unroll
    for (int i = 0; i < 4; i++) {
      afr[i] = *(const bf16_8*)&Ab[(wm + i * 16 + fr) * 32 + ach];
      bfr[i] = *(const bf16_8*)&Bb[(wn + i * 16 + fr) * 32 + ach];
    }
#pragma unroll
    for (int i = 0; i < 4; i++)
#pragma unroll
      for (int j = 0; j < 4; j++)
        acc[i][j] = __builtin_amdgcn_mfma_f32_16x16x32_bf16(afr[i], bfr[j], acc[i][j], 0, 0, 0);
  }

  // ---- epilogue stage 1: bias/relu/resid/stats in-reg, bf16 into swizzled LDS tile ----
  __syncthreads();                  // all frag reads of As/Bs retired -> safe to overwrite
  u16* Ct = smem;                   // [128][128] bf16, chunk index XOR (row&15)
  int rbase = lk * 4;
#pragma unroll
  for (int j = 0; j < 4; j++) {
    int colin = wn + j * 16 + fr;   // 0..127 block-local col
    int colg  = n0 + colin;         // global col
    float bv = bias[colg];
    float csum = 0.f, csq = 0.f;
#pragma unroll
    for (int i = 0; i < 4; i++) {
      int rowl = wm + i * 16 + rbase;
#pragma unroll
      for (int r = 0; r < 4; r++) {
        float c = acc[i][j][r] + bv;
        if (mode == 1) c = fmaxf(c, 0.f);
        if (mode == 2) {
          c += bf2f(resid[(size_t)(m0 + rowl + r) * 512 + colg]);
          csum += c; csq = fmaf(c, c, csq);
        }
        int rw = rowl + r;
        Ct[rw * 128 + (((colin >> 3) ^ (rw & 15)) << 3) + (colin & 7)] = f2bf(c);
      }
    }
    if (mode == 2) {
      csum += __shfl_xor(csum, 16); csum += __shfl_xor(csum, 32);
      csq  += __shfl_xor(csq, 16);  csq  += __shfl_xor(csq, 32);
      if (lk == 0) {
        atomicAdd(&stats[colg], csum);
        atomicAdd(&stats[512 + colg], csq);
      }
    }
  }
  __syncthreads();

  // ---- epilogue stage 2: wide coalesced stores; each wave-instr covers full sectors ----
#pragma unroll
  for (int rd = 0; rd < 8; rd++) {
    int lrow = w * 32 + rd * 4 + (lane >> 4);    // 0..127 block-local row
    int s = lane & 15;                            // swizzled chunk slot
    uint4 val = *(const uint4*)&Ct[lrow * 128 + s * 8];
    int chunk = s ^ (lrow & 15);                  // real 8-u16 chunk 0..15
    int grow = m0 + lrow;
    if (mode == 3) {
      int colg = n0 + chunk * 8;
      int cc = colg & 511;
      size_t idx = (size_t)(colg >> 9) * ((size_t)M_ * D_)
                 + ((size_t)((grow >> 8) * 8 + (cc >> 6)) * 256 + (grow & 255)) * 64 + (cc & 63);
      *(uint4*)&outb[idx] = val;
    } else {
      *(uint4*)&outb[(size_t)grow * 512 + n0 + chunk * 8] = val;
    }
  }
}

// ---------------- MFMA attention ----------------
// ROUND-6 BODY RESTORED (93 us, absmax 0.09375, bitwise-verified):
// full accS[16] scores, exact one-pass softmax, quarter-width Pm PV.
// Round-8 lesson: recompute-for-registers (2x QK^T) thrashed L2 (FETCH 49->115 MB)
// and doubled MFMA work — net -47%. Only change vs round 6: __launch_bounds__(256,3)
// asks the allocator for VGPR<=170 (natural was 176, live state ~134) -> 3 waves/SIMD
// instead of 2. Falsification signal: if FETCH jumps above ~55 MB, the cap spilled.
__global__ __launch_bounds__(256, 3) void k_attn(
    const u16* __restrict__ q, const u16* __restrict__ k,
    const u16* __restrict__ v, u16* __restrict__ attn)
{
  __shared__ u16 Vt[64 * 256];        // 32 KB  row=d (512B), chunk ck stores global ck^(row&31)
  __shared__ u16 Pm[4][16 * 64];      // 8 KB   per-wave P quarter, chunk c stores c^(row&7)
  int tid = threadIdx.x;
  int h = blockIdx.x & 7, b = blockIdx.x >> 3;
  size_t hb = (size_t)(b * 8 + h) * (256 * 64);
  int w = tid >> 6, lane = tid & 63;

  // ---- stage V transposed: Vt[d][key], keys packed pairwise as u32 ----
  {
    int kp = tid & 127;          // key pair index (keys 2kp, 2kp+1)
    int o  = tid >> 7;           // d half (0: d 0..31, 1: d 32..63)
    const u16* vp = v + hb + (size_t)(2 * kp) * 64 + o * 32;
    union { uint4 u[4]; u16 s[32]; } r0, r1;
#pragma unroll
    for (int i = 0; i < 4; i++) {
      r0.u[i] = *(const uint4*)(vp + i * 8);
      r1.u[i] = *(const uint4*)(vp + 64 + i * 8);
    }
#pragma unroll
    for (int d = 0; d < 32; d++) {
      int da = o * 32 + d;
      u32 val = (u32)r0.s[d] | ((u32)r1.s[d] << 16);
      int idx = da * 256 + ((((kp >> 2) ^ (da & 31)) << 3)) + ((2 * kp) & 7);
      *(u32*)&Vt[idx] = val;
    }
  }
  __syncthreads();   // Vt ds_writes visible block-wide

  int fr = lane & 15;          // fragment row/col
  int lk = lane >> 4;          // k-group
  int rbase = lk * 4;
  const u16* kb = k + hb;

#pragma unroll 1
  for (int qt = 0; qt < 4; qt++) {
    int q0 = qt * 64 + w * 16;   // sequence-local q-row base of this wave

    // ---- QK^T: S[16 x 256] per wave; K frags straight from global (L2) ----
    f32_4 accS[16];
    const u16* qbase = q + hb + (size_t)(q0 + fr) * 64 + lk * 8;
    bf16_8 af0 = *(const bf16_8*)(qbase);
    bf16_8 af1 = *(const bf16_8*)(qbase + 32);
#pragma unroll
    for (int j = 0; j < 16; j++) {
      const u16* kr = kb + (size_t)(j * 16 + fr) * 64;
      bf16_8 bf0 = *(const bf16_8*)(kr + lk * 8);
      bf16_8 bf1 = *(const bf16_8*)(kr + 32 + lk * 8);
      f32_4 z = {};
      z = __builtin_amdgcn_mfma_f32_16x16x32_bf16(af0, bf0, z, 0, 0, 0);
      accS[j] = __builtin_amdgcn_mfma_f32_16x16x32_bf16(af1, bf1, z, 0, 0, 0);
    }

    // ---- softmax over keys ----
    float l[4];
#pragma unroll
    for (int r = 0; r < 4; r++) {
      float m = accS[0][r];
#pragma unroll
      for (int j = 1; j < 16; j++) m = fmaxf(m, accS[j][r]);
      m = fmaxf(m, __shfl_xor(m, 1));
      m = fmaxf(m, __shfl_xor(m, 2));
      m = fmaxf(m, __shfl_xor(m, 4));
      m = fmaxf(m, __shfl_xor(m, 8));
      float s = 0.f;
#pragma unroll
      for (int j = 0; j < 16; j++) {
        float p = __expf((accS[j][r] - m) * 0.125f);   // 1/sqrt(64)
        accS[j][r] = p;
        s += p;
      }
      s += __shfl_xor(s, 1);
      s += __shfl_xor(s, 2);
      s += __shfl_xor(s, 4);
      s += __shfl_xor(s, 8);
      l[r] = s;
    }

    // ---- PV in four key-quarters through quarter-width Pm (wave-private, no barrier) ----
    f32_4 accO[4] = {};
#pragma unroll
    for (int hs = 0; hs < 4; hs++) {
      // write P quarter (C-layout -> swizzled LDS), own rows only
#pragma unroll
      for (int j4 = 0; j4 < 4; j4++) {
        int col = j4 * 16 + fr;       // 0..63 within quarter
        int ch = col >> 3, cl = col & 7;
#pragma unroll
        for (int r = 0; r < 4; r++) {
          int row = rbase + r;        // 0..15 within wave region
          Pm[w][row * 64 + ((ch ^ (row & 7)) << 3) + cl] = f2bf(accS[hs * 4 + j4][r]);
        }
      }
      // PV over this quarter's 64 keys (2 mfma K-steps)
#pragma unroll
      for (int kk = 0; kk < 2; kk++) {
        bf16_8 pa = *(const bf16_8*)&Pm[w][fr * 64 + (((kk * 4 + lk) ^ (fr & 7)) << 3)];
#pragma unroll
        for (int jd = 0; jd < 4; jd++) {
          int brow = jd * 16 + fr;
          int ck = hs * 8 + kk * 4 + lk;
          bf16_8 vb = *(const bf16_8*)&Vt[brow * 256 + ((ck ^ (brow & 31)) << 3)];
          accO[jd] = __builtin_amdgcn_mfma_f32_16x16x32_bf16(pa, vb, accO[jd], 0, 0, 0);
        }
      }
    }

    // ---- epilogue: normalize by l, store bf16 to [M,512] ----
    float linv[4];
#pragma unroll
    for (int r = 0; r < 4; r++) linv[r] = 1.f / l[r];
    size_t orow0 = (size_t)(b * S_ + q0 + rbase);
#pragma unroll
    for (int jd = 0; jd < 4; jd++) {
      int col = h * DH_ + jd * 16 + fr;
#pragma unroll
      for (int r = 0; r < 4; r++)
        attn[(orow0 + r) * D_ + col] = f2bf(accO[jd][r] * linv[r]);
    }
  }
}

// ---------------- batchnorm ----------------
__global__ __launch_bounds__(256) void k_zero(float* p, int n) {
  int t = blockIdx.x * 256 + threadIdx.x;
  if (t < n) p[t] = 0.f;
}

// 8 elems/thread; P is bf16 pre-BN. Writes bf16 (outb) when outf==nullptr,
// else f32 (final layer).
__global__ __launch_bounds__(256) void k_bnapply(const u16* __restrict__ P,
    const float* __restrict__ stats, const float* __restrict__ gamma,
    const float* __restrict__ beta, u16* __restrict__ outb, float* __restrict__ outf)
{
  size_t t8 = ((size_t)blockIdx.x * 256 + threadIdx.x) * 8;
  int f = (int)(t8 & 511);
  const float inv = 1.f / 32768.f;
  float sc[8], sh[8];
#pragma unroll
  for (int i = 0; i < 8; i++) {
    float mu = stats[f + i] * inv;
    float var = stats[512 + f + i] * inv - mu * mu;
    sc[i] = gamma[f + i] * rsqrtf(var + EPS_);
    sh[i] = beta[f + i] - mu * sc[i];
  }
  union { uint4 u; u16 s[8]; } pv;
  pv.u = *(const uint4*)&P[t8];
  float o[8];
#pragma unroll
  for (int i = 0; i < 8; i++) o[i] = bf2f(pv.s[i]) * sc[i] + sh[i];
  if (outf) {
    *(float4*)&outf[t8]     = make_float4(o[0], o[1], o[2], o[3]);
    *(float4*)&outf[t8 + 4] = make_float4(o[4], o[5], o[6], o[7]);
  } else {
    u32 u[4];
#pragma unroll
    for (int i = 0; i < 4; i++)
      u[i] = (u32)f2bf(o[2 * i]) | ((u32)f2bf(o[2 * i + 1]) << 16);
    *(uint4*)&outb[t8] = make_uint4(u[0], u[1], u[2], u[3]);
  }
}

// ---------------- launch ----------------
extern "C" void kernel_launch(void* const* d_in, const int* in_sizes, int n_in,
                              void* d_out, int out_size, void* d_ws, size_t ws_size,
                              hipStream_t stream)
{
  const int*   seq = (const int*)d_in[0];
  const float* pos = (const float*)d_in[1];
  const float* emb = (const float*)d_in[2];
  const float* Wq  = (const float*)d_in[3];
  const float* bq  = (const float*)d_in[4];
  const float* Wk  = (const float*)d_in[5];
  const float* bk  = (const float*)d_in[6];
  const float* Wv  = (const float*)d_in[7];
  const float* bv  = (const float*)d_in[8];
  const float* Wo  = (const float*)d_in[9];
  const float* bo  = (const float*)d_in[10];
  const float* g1  = (const float*)d_in[11];
  const float* be1 = (const float*)d_in[12];
  const float* W1  = (const float*)d_in[13];
  const float* b1  = (const float*)d_in[14];
  const float* W2  = (const float*)d_in[15];
  const float* b2  = (const float*)d_in[16];
  const float* g2  = (const float*)d_in[17];
  const float* be2 = (const float*)d_in[18];

  char* ws = (char*)d_ws;
  const size_t SZH = (size_t)M_ * D_ * 2;        // 32 MiB per bf16 activation
  u16* hb16 = (u16*)(ws);                        // master activation (bf16)
  u16* qB   = (u16*)(ws + SZH);                  // q,k,v contiguous (fused QKV writes all 3)
  u16* kB   = (u16*)(ws + 2 * SZH);
  u16* vB   = (u16*)(ws + 3 * SZH);
  u16* aB   = (u16*)(ws + 4 * SZH);
  u16* PB   = (u16*)(ws + 2 * SZH);              // bf16 pre-BN, overlays kB (dead then)
  u16* tB   = qB;                                // FFN hidden reuses q
  u16* Wt   = (u16*)(ws + 5 * SZH);
  float* stats = (float*)(ws + 5 * SZH + (size_t)24 * D_ * D_ * 2);
  float* bqkv  = stats + 8192;                   // [L][1536] packed QKV bias

  dim3 blk(256);
  k_zero<<<32, blk, 0, stream>>>(stats, 8192);
  k_packbias<<<24, blk, 0, stream>>>(bq, bk, bv, bqkv);
  k_transpose<<<dim3(16, 16, 24), blk, 0, stream>>>(Wq, Wk, Wv, Wo, W1, W2, Wt);
  k_embed<<<M_ * 64 / 256, blk, 0, stream>>>(seq, pos, emb, hb16);

  dim3 ggrid(512 / 128, M_ / 128);    // (N-tiles, M-tiles): consecutive blocks share A m-tile
  dim3 qgrid(1536 / 128, M_ / 128);
  for (int l = 0; l < L_; l++) {
    const u16* wtqkv = Wt + (size_t)(l * 6 + 0) * D_ * D_;   // Wq^T|Wk^T|Wv^T contiguous
    const u16* wto = Wt + (size_t)(l * 6 + 3) * D_ * D_;
    const u16* wt1 = Wt + (size_t)(l * 6 + 4) * D_ * D_;
    const u16* wt2 = Wt + (size_t)(l * 6 + 5) * D_ * D_;
    float* st = stats + l * 2048;

    k_gemm<<<qgrid, blk, 0, stream>>>(hb16, wtqkv, bqkv + l * 1536, nullptr, qB, nullptr, 3);
    k_attn<<<B_ * H_, blk, 0, stream>>>(qB, kB, vB, aB);
    k_gemm<<<ggrid, blk, 0, stream>>>(aB, wto, bo + l * D_, hb16, PB, st, 2);
    k_bnapply<<<8192, blk, 0, stream>>>(PB, st, g1 + l * D_, be1 + l * D_, hb16, nullptr);
    k_gemm<<<ggrid, blk, 0, stream>>>(hb16, wt1, b1 + l * FF_, nullptr, tB, nullptr, 1);
    k_gemm<<<ggrid, blk, 0, stream>>>(tB, wt2, b2 + l * D_, hb16, PB, st + 1024, 2);
    if (l == L_ - 1)
      k_bnapply<<<8192, blk, 0, stream>>>(PB, st + 1024, g2 + l * D_, be2 + l * D_, nullptr, (float*)d_out);
    else
      k_bnapply<<<8192, blk, 0, stream>>>(PB, st + 1024, g2 + l * D_, be2 + l * D_, hb16, nullptr);
  }
}

// Round 11
// 1529.286 us; speedup vs baseline: 1.1804x; 1.1804x over previous
//
#include <hip/hip_runtime.h>

#define B_   128
#define S_   256
#define D_   512
#define L_   4
#define H_   8
#define DH_  64
#define FF_  512
#define M_   32768   // B_*S_
#define EPS_ 1e-3f

typedef unsigned short u16;
typedef unsigned int   u32;
typedef __bf16 bf16_8 __attribute__((ext_vector_type(8)));
typedef float  f32_4  __attribute__((ext_vector_type(4)));

__device__ __forceinline__ float bf2f(u16 u) {
  union { u32 i; float f; } x; x.i = ((u32)u) << 16; return x.f;
}
__device__ __forceinline__ u16 f2bf(float f) {
  union { float f; u32 i; } x; x.f = f;
  u32 r = x.i + 0x7fffu + ((x.i >> 16) & 1u);
  return (u16)(r >> 16);
}
// async 16B global->LDS; lane i of the wave lands at l + i*16 bytes
__device__ __forceinline__ void async_cp16(const void* g, void* l) {
  __builtin_amdgcn_global_load_lds(
      (const __attribute__((address_space(1))) void*)g,
      (__attribute__((address_space(3))) void*)l, 16, 0, 0);
}

// ---------------- embedding: h_bf16 = bf16(embed[seq] + pos), f32 inputs ----------------
__global__ __launch_bounds__(256) void k_embed(const int* __restrict__ seq,
    const float* __restrict__ pos, const float* __restrict__ emb,
    u16* __restrict__ h)
{
  int t = blockIdx.x * 256 + threadIdx.x;   // M_*64 threads, 8 elems each
  int row = t >> 6;
  int c = (t & 63) * 8;
  int s = row & (S_ - 1);
  int tok = seq[row];
  const float* ep = emb + (size_t)tok * D_ + c;
  const float* pp = pos + (size_t)s * D_ + c;
  float4 e0 = *(const float4*)ep;
  float4 e1 = *(const float4*)(ep + 4);
  float4 p0 = *(const float4*)pp;
  float4 p1 = *(const float4*)(pp + 4);
  u32 o[4];
  o[0] = (u32)f2bf(e0.x + p0.x) | ((u32)f2bf(e0.y + p0.y) << 16);
  o[1] = (u32)f2bf(e0.z + p0.z) | ((u32)f2bf(e0.w + p0.w) << 16);
  o[2] = (u32)f2bf(e1.x + p1.x) | ((u32)f2bf(e1.y + p1.y) << 16);
  o[3] = (u32)f2bf(e1.z + p1.z) | ((u32)f2bf(e1.w + p1.w) << 16);
  *(uint4*)&h[(size_t)row * D_ + c] = make_uint4(o[0], o[1], o[2], o[3]);
}

// ------- transpose all 24 [512x512] f32 weights -> bf16 Wt[n][k] -------
__global__ __launch_bounds__(256) void k_transpose(
    const float* __restrict__ Wq, const float* __restrict__ Wk, const float* __restrict__ Wv,
    const float* __restrict__ Wo, const float* __restrict__ W1, const float* __restrict__ W2,
    u16* __restrict__ Wt)
{
  __shared__ u16 tile[32][33];
  int mat = blockIdx.z;           // 0..23
  int layer = mat / 6, w = mat % 6;
  const float* src = (w == 0) ? Wq : (w == 1) ? Wk : (w == 2) ? Wv
                   : (w == 3) ? Wo : (w == 4) ? W1 : W2;
  src += (size_t)layer * (D_ * D_);
  u16* dst = Wt + (size_t)mat * (D_ * D_);
  int bx = blockIdx.x * 32;   // n
  int by = blockIdx.y * 32;   // k
  int tx = threadIdx.x & 31, ty = threadIdx.x >> 5;
#pragma unroll
  for (int i = 0; i < 32; i += 8)
    tile[ty + i][tx] = f2bf(src[(size_t)(by + ty + i) * D_ + bx + tx]);
  __syncthreads();
#pragma unroll
  for (int i = 0; i < 32; i += 8)
    dst[(size_t)(bx + ty + i) * D_ + by + tx] = tile[tx][ty + i];
}

// ------- pack per-layer QKV bias into [L][1536] -------
__global__ __launch_bounds__(256) void k_packbias(const float* __restrict__ bq,
    const float* __restrict__ bk, const float* __restrict__ bv, float* __restrict__ dst)
{
  int t = blockIdx.x * 256 + threadIdx.x;   // 4*1536 = 6144
  int l = t / 1536, j = t - l * 1536;
  const float* src = (j < 512) ? bq : (j < 1024) ? bk : bv;
  dst[t] = src[l * 512 + (j & 511)];
}

// ---------------- GEMM: C[M,N] = A[M,512](bf16) x Bt[n][k](bf16) + bias(f32) ----------------
// mode 0: outb bf16 = A*B + bias                      (row-major [M,512])
// mode 1: outb bf16 = relu(A*B + bias)                (row-major [M,512])
// mode 2: outb bf16 = A*B + bias + resid(bf16) (pre-BN value), BN-stat atomics into stats[]
// mode 3: fused QKV (N=1536): outb bf16 head-blocked [b,h,s,dh]; col>>9 selects
//         the q/k/v output buffer (contiguous at stride M_*D_ from outb)
// K-loop: 3-buffer distance-2 prefetch, counted vmcnt (verified round 4).
// Epilogue: acc -> swizzled LDS C-tile -> full-sector uint4 stores (verified round 6).
// Grid is (N-tiles, M-tiles): consecutive blocks share the A m-tile (L2-hot).
__global__ __launch_bounds__(256) void k_gemm(
    const u16* __restrict__ A, const u16* __restrict__ Bt,
    const float* __restrict__ bias, const u16* __restrict__ resid,
    u16* __restrict__ outb, float* __restrict__ stats,
    int mode)
{
  __shared__ __align__(16) u16 smem[24576];   // As(12288) | Bs(12288); epilogue Ct[128][128]
  u16* As = smem;
  u16* Bs = smem + 12288;
  int tid = threadIdx.x;
  int m0 = blockIdx.y * 128;
  int n0 = blockIdx.x * 128;
  int w = tid >> 6, lane = tid & 63;
  int wm = (w >> 1) * 64, wn = (w & 1) * 64;
  int fr = lane & 15, lk = lane >> 4;

  // staging: wave w stages rows [w*32, w*32+32) of A and B tiles via 2 cp16 each.
  int srow = lane >> 2;                          // 0..15 within 16-row window
  int schunk = (lane & 3) ^ ((lane >> 4) & 3);   // swizzled 16B chunk within 64B row
  const u16* Ag0 = A  + (size_t)(m0 + w * 32 + srow) * 512 + schunk * 8;
  const u16* Ag1 = Ag0 + (size_t)16 * 512;
  const u16* Bg0 = Bt + (size_t)(n0 + w * 32 + srow) * 512 + schunk * 8;
  const u16* Bg1 = Bg0 + (size_t)16 * 512;
  int off0 = (w * 32) * 32;
  int off1 = (w * 32 + 16) * 32;

  f32_4 acc[4][4] = {};
  int ach = (lk ^ ((fr >> 2) & 3)) * 8;          // frag chunk (elements) after swizzle

  // prologue: stage k-tiles 0,1 into buffers 0,1 (8 loads in flight/wave)
  async_cp16(Ag0, &As[off0]);
  async_cp16(Ag1, &As[off1]);
  async_cp16(Bg0, &Bs[off0]);
  async_cp16(Bg1, &Bs[off1]);
  async_cp16(Ag0 + 32, &As[4096 + off0]);
  async_cp16(Ag1 + 32, &As[4096 + off1]);
  async_cp16(Bg0 + 32, &Bs[4096 + off0]);
  async_cp16(Bg1 + 32, &Bs[4096 + off1]);

#pragma unroll
  for (int it = 0; it < 16; it++) {
    // wait for the OLDEST tile only: tile it's 4 loads done, tile it+1's may fly
    if (it < 15) asm volatile("s_waitcnt vmcnt(4)" ::: "memory");
    else         asm volatile("s_waitcnt vmcnt(0)" ::: "memory");
    __builtin_amdgcn_s_barrier();
    asm volatile("" ::: "memory");   // fence: no LDS-read hoisting above barrier
    if (it < 14) {                   // stage tile it+2 into buffer (it+2)%3
      int kn = (it + 2) * 32;
      int pn = ((it + 2) % 3) * 4096;
      async_cp16(Ag0 + kn, &As[pn + off0]);
      async_cp16(Ag1 + kn, &As[pn + off1]);
      async_cp16(Bg0 + kn, &Bs[pn + off0]);
      async_cp16(Bg1 + kn, &Bs[pn + off1]);
    }
    const u16* Ab = &As[(it % 3) * 4096];
    const u16* Bb = &Bs[(it % 3) * 4096];
    bf16_8 afr[4], bfr[4];
#pragma unroll
    for (int i = 0; i < 4; i++) {
      afr[i] = *(const bf16_8*)&Ab[(wm + i * 16 + fr) * 32 + ach];
      bfr[i] = *(const bf16_8*)&Bb[(wn + i * 16 + fr) * 32 + ach];
    }
#pragma unroll
    for (int i = 0; i < 4; i++)
#pragma unroll
      for (int j = 0; j < 4; j++)
        acc[i][j] = __builtin_amdgcn_mfma_f32_16x16x32_bf16(afr[i], bfr[j], acc[i][j], 0, 0, 0);
  }

  // ---- epilogue stage 1: bias/relu/resid/stats in-reg, bf16 into swizzled LDS tile ----
  __syncthreads();                  // all frag reads of As/Bs retired -> safe to overwrite
  u16* Ct = smem;                   // [128][128] bf16, chunk index XOR (row&15)
  int rbase = lk * 4;
#pragma unroll
  for (int j = 0; j < 4; j++) {
    int colin = wn + j * 16 + fr;   // 0..127 block-local col
    int colg  = n0 + colin;         // global col
    float bv = bias[colg];
    float csum = 0.f, csq = 0.f;
#pragma unroll
    for (int i = 0; i < 4; i++) {
      int rowl = wm + i * 16 + rbase;
#pragma unroll
      for (int r = 0; r < 4; r++) {
        float c = acc[i][j][r] + bv;
        if (mode == 1) c = fmaxf(c, 0.f);
        if (mode == 2) {
          c += bf2f(resid[(size_t)(m0 + rowl + r) * 512 + colg]);
          csum += c; csq = fmaf(c, c, csq);
        }
        int rw = rowl + r;
        Ct[rw * 128 + (((colin >> 3) ^ (rw & 15)) << 3) + (colin & 7)] = f2bf(c);
      }
    }
    if (mode == 2) {
      csum += __shfl_xor(csum, 16); csum += __shfl_xor(csum, 32);
      csq  += __shfl_xor(csq, 16);  csq  += __shfl_xor(csq, 32);
      if (lk == 0) {
        atomicAdd(&stats[colg], csum);
        atomicAdd(&stats[512 + colg], csq);
      }
    }
  }
  __syncthreads();

  // ---- epilogue stage 2: wide coalesced stores; each wave-instr covers full sectors ----
#pragma unroll
  for (int rd = 0; rd < 8; rd++) {
    int lrow = w * 32 + rd * 4 + (lane >> 4);    // 0..127 block-local row
    int s = lane & 15;                            // swizzled chunk slot
    uint4 val = *(const uint4*)&Ct[lrow * 128 + s * 8];
    int chunk = s ^ (lrow & 15);                  // real 8-u16 chunk 0..15
    int grow = m0 + lrow;
    if (mode == 3) {
      int colg = n0 + chunk * 8;
      int cc = colg & 511;
      size_t idx = (size_t)(colg >> 9) * ((size_t)M_ * D_)
                 + ((size_t)((grow >> 8) * 8 + (cc >> 6)) * 256 + (grow & 255)) * 64 + (cc & 63);
      *(uint4*)&outb[idx] = val;
    } else {
      *(uint4*)&outb[(size_t)grow * 512 + n0 + chunk * 8] = val;
    }
  }
}

// ---------------- MFMA attention ----------------
// ROUND-6 BODY RESTORED EXACTLY (93 us, absmax 0.09375): full accS[16] scores,
// exact one-pass softmax, quarter-width Pm PV, natural VGPR (plain launch bounds).
// Occupancy series CLOSED: HW occupancy steps are at VGPR {64,128,256} (2/4/8
// waves per SIMD) — 4 waves needs <=128 VGPR, below the ~134 live state; both
// forcing (rounds 2/9: spill, FETCH 49->250+ MB) and recompute (round 8: L2
// thrash) were net-negative. Only addition vs round 6: s_setprio(1/0) around the
// MFMA clusters (scheduling hint, no correctness surface; attn waves here are
// barrier-free/phase-diverse — the regime where it measured +4-7%).
__global__ __launch_bounds__(256) void k_attn(
    const u16* __restrict__ q, const u16* __restrict__ k,
    const u16* __restrict__ v, u16* __restrict__ attn)
{
  __shared__ u16 Vt[64 * 256];        // 32 KB  row=d (512B), chunk ck stores global ck^(row&31)
  __shared__ u16 Pm[4][16 * 64];      // 8 KB   per-wave P quarter, chunk c stores c^(row&7)
  int tid = threadIdx.x;
  int h = blockIdx.x & 7, b = blockIdx.x >> 3;
  size_t hb = (size_t)(b * 8 + h) * (256 * 64);
  int w = tid >> 6, lane = tid & 63;

  // ---- stage V transposed: Vt[d][key], keys packed pairwise as u32 ----
  {
    int kp = tid & 127;          // key pair index (keys 2kp, 2kp+1)
    int o  = tid >> 7;           // d half (0: d 0..31, 1: d 32..63)
    const u16* vp = v + hb + (size_t)(2 * kp) * 64 + o * 32;
    union { uint4 u[4]; u16 s[32]; } r0, r1;
#pragma unroll
    for (int i = 0; i < 4; i++) {
      r0.u[i] = *(const uint4*)(vp + i * 8);
      r1.u[i] = *(const uint4*)(vp + 64 + i * 8);
    }
#pragma unroll
    for (int d = 0; d < 32; d++) {
      int da = o * 32 + d;
      u32 val = (u32)r0.s[d] | ((u32)r1.s[d] << 16);
      int idx = da * 256 + ((((kp >> 2) ^ (da & 31)) << 3)) + ((2 * kp) & 7);
      *(u32*)&Vt[idx] = val;
    }
  }
  __syncthreads();   // Vt ds_writes visible block-wide

  int fr = lane & 15;          // fragment row/col
  int lk = lane >> 4;          // k-group
  int rbase = lk * 4;
  const u16* kb = k + hb;

#pragma unroll 1
  for (int qt = 0; qt < 4; qt++) {
    int q0 = qt * 64 + w * 16;   // sequence-local q-row base of this wave

    // ---- QK^T: S[16 x 256] per wave; K frags straight from global (L2) ----
    f32_4 accS[16];
    const u16* qbase = q + hb + (size_t)(q0 + fr) * 64 + lk * 8;
    bf16_8 af0 = *(const bf16_8*)(qbase);
    bf16_8 af1 = *(const bf16_8*)(qbase + 32);
    __builtin_amdgcn_s_setprio(1);
#pragma unroll
    for (int j = 0; j < 16; j++) {
      const u16* kr = kb + (size_t)(j * 16 + fr) * 64;
      bf16_8 bf0 = *(const bf16_8*)(kr + lk * 8);
      bf16_8 bf1 = *(const bf16_8*)(kr + 32 + lk * 8);
      f32_4 z = {};
      z = __builtin_amdgcn_mfma_f32_16x16x32_bf16(af0, bf0, z, 0, 0, 0);
      accS[j] = __builtin_amdgcn_mfma_f32_16x16x32_bf16(af1, bf1, z, 0, 0, 0);
    }
    __builtin_amdgcn_s_setprio(0);

    // ---- softmax over keys ----
    float l[4];
#pragma unroll
    for (int r = 0; r < 4; r++) {
      float m = accS[0][r];
#pragma unroll
      for (int j = 1; j < 16; j++) m = fmaxf(m, accS[j][r]);
      m = fmaxf(m, __shfl_xor(m, 1));
      m = fmaxf(m, __shfl_xor(m, 2));
      m = fmaxf(m, __shfl_xor(m, 4));
      m = fmaxf(m, __shfl_xor(m, 8));
      float s = 0.f;
#pragma unroll
      for (int j = 0; j < 16; j++) {
        float p = __expf((accS[j][r] - m) * 0.125f);   // 1/sqrt(64)
        accS[j][r] = p;
        s += p;
      }
      s += __shfl_xor(s, 1);
      s += __shfl_xor(s, 2);
      s += __shfl_xor(s, 4);
      s += __shfl_xor(s, 8);
      l[r] = s;
    }

    // ---- PV in four key-quarters through quarter-width Pm (wave-private, no barrier) ----
    f32_4 accO[4] = {};
#pragma unroll
    for (int hs = 0; hs < 4; hs++) {
      // write P quarter (C-layout -> swizzled LDS), own rows only
#pragma unroll
      for (int j4 = 0; j4 < 4; j4++) {
        int col = j4 * 16 + fr;       // 0..63 within quarter
        int ch = col >> 3, cl = col & 7;
#pragma unroll
        for (int r = 0; r < 4; r++) {
          int row = rbase + r;        // 0..15 within wave region
          Pm[w][row * 64 + ((ch ^ (row & 7)) << 3) + cl] = f2bf(accS[hs * 4 + j4][r]);
        }
      }
      // PV over this quarter's 64 keys (2 mfma K-steps)
      __builtin_amdgcn_s_setprio(1);
#pragma unroll
      for (int kk = 0; kk < 2; kk++) {
        bf16_8 pa = *(const bf16_8*)&Pm[w][fr * 64 + (((kk * 4 + lk) ^ (fr & 7)) << 3)];
#pragma unroll
        for (int jd = 0; jd < 4; jd++) {
          int brow = jd * 16 + fr;
          int ck = hs * 8 + kk * 4 + lk;
          bf16_8 vb = *(const bf16_8*)&Vt[brow * 256 + ((ck ^ (brow & 31)) << 3)];
          accO[jd] = __builtin_amdgcn_mfma_f32_16x16x32_bf16(pa, vb, accO[jd], 0, 0, 0);
        }
      }
      __builtin_amdgcn_s_setprio(0);
    }

    // ---- epilogue: normalize by l, store bf16 to [M,512] ----
    float linv[4];
#pragma unroll
    for (int r = 0; r < 4; r++) linv[r] = 1.f / l[r];
    size_t orow0 = (size_t)(b * S_ + q0 + rbase);
#pragma unroll
    for (int jd = 0; jd < 4; jd++) {
      int col = h * DH_ + jd * 16 + fr;
#pragma unroll
      for (int r = 0; r < 4; r++)
        attn[(orow0 + r) * D_ + col] = f2bf(accO[jd][r] * linv[r]);
    }
  }
}

// ---------------- batchnorm ----------------
__global__ __launch_bounds__(256) void k_zero(float* p, int n) {
  int t = blockIdx.x * 256 + threadIdx.x;
  if (t < n) p[t] = 0.f;
}

// 8 elems/thread; P is bf16 pre-BN. Writes bf16 (outb) when outf==nullptr,
// else f32 (final layer).
__global__ __launch_bounds__(256) void k_bnapply(const u16* __restrict__ P,
    const float* __restrict__ stats, const float* __restrict__ gamma,
    const float* __restrict__ beta, u16* __restrict__ outb, float* __restrict__ outf)
{
  size_t t8 = ((size_t)blockIdx.x * 256 + threadIdx.x) * 8;
  int f = (int)(t8 & 511);
  const float inv = 1.f / 32768.f;
  float sc[8], sh[8];
#pragma unroll
  for (int i = 0; i < 8; i++) {
    float mu = stats[f + i] * inv;
    float var = stats[512 + f + i] * inv - mu * mu;
    sc[i] = gamma[f + i] * rsqrtf(var + EPS_);
    sh[i] = beta[f + i] - mu * sc[i];
  }
  union { uint4 u; u16 s[8]; } pv;
  pv.u = *(const uint4*)&P[t8];
  float o[8];
#pragma unroll
  for (int i = 0; i < 8; i++) o[i] = bf2f(pv.s[i]) * sc[i] + sh[i];
  if (outf) {
    *(float4*)&outf[t8]     = make_float4(o[0], o[1], o[2], o[3]);
    *(float4*)&outf[t8 + 4] = make_float4(o[4], o[5], o[6], o[7]);
  } else {
    u32 u[4];
#pragma unroll
    for (int i = 0; i < 4; i++)
      u[i] = (u32)f2bf(o[2 * i]) | ((u32)f2bf(o[2 * i + 1]) << 16);
    *(uint4*)&outb[t8] = make_uint4(u[0], u[1], u[2], u[3]);
  }
}

// ---------------- launch ----------------
extern "C" void kernel_launch(void* const* d_in, const int* in_sizes, int n_in,
                              void* d_out, int out_size, void* d_ws, size_t ws_size,
                              hipStream_t stream)
{
  const int*   seq = (const int*)d_in[0];
  const float* pos = (const float*)d_in[1];
  const float* emb = (const float*)d_in[2];
  const float* Wq  = (const float*)d_in[3];
  const float* bq  = (const float*)d_in[4];
  const float* Wk  = (const float*)d_in[5];
  const float* bk  = (const float*)d_in[6];
  const float* Wv  = (const float*)d_in[7];
  const float* bv  = (const float*)d_in[8];
  const float* Wo  = (const float*)d_in[9];
  const float* bo  = (const float*)d_in[10];
  const float* g1  = (const float*)d_in[11];
  const float* be1 = (const float*)d_in[12];
  const float* W1  = (const float*)d_in[13];
  const float* b1  = (const float*)d_in[14];
  const float* W2  = (const float*)d_in[15];
  const float* b2  = (const float*)d_in[16];
  const float* g2  = (const float*)d_in[17];
  const float* be2 = (const float*)d_in[18];

  char* ws = (char*)d_ws;
  const size_t SZH = (size_t)M_ * D_ * 2;        // 32 MiB per bf16 activation
  u16* hb16 = (u16*)(ws);                        // master activation (bf16)
  u16* qB   = (u16*)(ws + SZH);                  // q,k,v contiguous (fused QKV writes all 3)
  u16* kB   = (u16*)(ws + 2 * SZH);
  u16* vB   = (u16*)(ws + 3 * SZH);
  u16* aB   = (u16*)(ws + 4 * SZH);
  u16* PB   = (u16*)(ws + 2 * SZH);              // bf16 pre-BN, overlays kB (dead then)
  u16* tB   = qB;                                // FFN hidden reuses q
  u16* Wt   = (u16*)(ws + 5 * SZH);
  float* stats = (float*)(ws + 5 * SZH + (size_t)24 * D_ * D_ * 2);
  float* bqkv  = stats + 8192;                   // [L][1536] packed QKV bias

  dim3 blk(256);
  k_zero<<<32, blk, 0, stream>>>(stats, 8192);
  k_packbias<<<24, blk, 0, stream>>>(bq, bk, bv, bqkv);
  k_transpose<<<dim3(16, 16, 24), blk, 0, stream>>>(Wq, Wk, Wv, Wo, W1, W2, Wt);
  k_embed<<<M_ * 64 / 256, blk, 0, stream>>>(seq, pos, emb, hb16);

  dim3 ggrid(512 / 128, M_ / 128);    // (N-tiles, M-tiles): consecutive blocks share A m-tile
  dim3 qgrid(1536 / 128, M_ / 128);
  for (int l = 0; l < L_; l++) {
    const u16* wtqkv = Wt + (size_t)(l * 6 + 0) * D_ * D_;   // Wq^T|Wk^T|Wv^T contiguous
    const u16* wto = Wt + (size_t)(l * 6 + 3) * D_ * D_;
    const u16* wt1 = Wt + (size_t)(l * 6 + 4) * D_ * D_;
    const u16* wt2 = Wt + (size_t)(l * 6 + 5) * D_ * D_;
    float* st = stats + l * 2048;

    k_gemm<<<qgrid, blk, 0, stream>>>(hb16, wtqkv, bqkv + l * 1536, nullptr, qB, nullptr, 3);
    k_attn<<<B_ * H_, blk, 0, stream>>>(qB, kB, vB, aB);
    k_gemm<<<ggrid, blk, 0, stream>>>(aB, wto, bo + l * D_, hb16, PB, st, 2);
    k_bnapply<<<8192, blk, 0, stream>>>(PB, st, g1 + l * D_, be1 + l * D_, hb16, nullptr);
    k_gemm<<<ggrid, blk, 0, stream>>>(hb16, wt1, b1 + l * FF_, nullptr, tB, nullptr, 1);
    k_gemm<<<ggrid, blk, 0, stream>>>(tB, wt2, b2 + l * D_, hb16, PB, st + 1024, 2);
    if (l == L_ - 1)
      k_bnapply<<<8192, blk, 0, stream>>>(PB, st + 1024, g2 + l * D_, be2 + l * D_, nullptr, (float*)d_out);
    else
      k_bnapply<<<8192, blk, 0, stream>>>(PB, st + 1024, g2 + l * D_, be2 + l * D_, hb16, nullptr);
  }
}